// Round 7
// baseline (260.382 us; speedup 1.0000x reference)
//
#include <hip/hip_runtime.h>

// Causal SDPA: B=4,H=16,S=2048,D=64, fp32 in/out.
// Flash attention, bf16 mfma 16x16x32, swapped QK^T (S^T = K.Q) with permuted
// K staging so P feeds PV directly. KVBLK=64, exp2-domain softmax,
// XOR-swizzled 16B-cell LDS (conflict-free), double-buffered with
// prefetch-to-regs, 1 barrier/iter, defer-rescale, setprio, MFMA row-sum.
// Round 7: 16 q-rows/wave (64/block), paired q-tiles (31-p,p) -> uniform 33
// iters, grid 1024 -> 4 blocks/CU = 4 waves/SIMD (2x TLP of round 6).

#define SEQ 2048
#define HD  64

typedef __attribute__((ext_vector_type(8))) short short8;
typedef __attribute__((ext_vector_type(4))) float f32x4;
typedef __attribute__((ext_vector_type(2))) float f32x2;
typedef __attribute__((ext_vector_type(2))) __bf16 bf16x2;

__device__ __forceinline__ unsigned pk2(float lo, float hi) {
    union { bf16x2 v; unsigned u; } r;
    r.v = __builtin_convertvector((f32x2){lo, hi}, bf16x2);
    return r.u;
}

// Per buffer: K tile 8192 B + V^T tile 8192 B. Cells are 16 B (8 bf16),
// XOR-swizzled: cell addr = (row*8 + (unit ^ (row&7))) * 16.
__global__ __launch_bounds__(256, 4) void sdpa_kernel(
    const float* __restrict__ Q, const float* __restrict__ K,
    const float* __restrict__ V, float* __restrict__ O)
{
    __shared__ __align__(16) char smraw[32768];

    const int bx = blockIdx.x;
    const int p  = bx >> 6;               // 0..15: q-tile pair (31-p, p)
    const int bh = bx & 63;

    const int tid  = threadIdx.x;
    const int lane = tid & 63;
    const int w    = tid >> 6;
    const int g    = lane >> 4;
    const int r16  = lane & 15;

    const size_t base = (size_t)bh * (SEQ * HD);

    // staging thread assignments (fixed per thread)
    const int k_kvo = tid >> 2;
    const int k_o   = k_kvo & 31;
    const int k_row = (k_kvo & 32) + 16 * ((k_o >> 2) & 1) + 4 * (k_o >> 3) + (k_o & 3);
    const int k_dc  = (tid & 3) * 2;
    const int v_kv0 = (tid & 31) * 2;
    const int v_db  = (tid >> 5) * 8;

    // ones bf16 fragment for MFMA row-sum of P
    short8 ones;
    { union { short8 s; unsigned u[4]; } o_;
      o_.u[0] = o_.u[1] = o_.u[2] = o_.u[3] = 0x3F803F80u; ones = o_.s; }

    // prefetch registers (held across compute)
    f32x4 ka0, ka1, kb0, kb1, va0, va1, vb0, vb1;

    auto LOADT = [&](int kvbase) {
        const float* kp = K + base + (size_t)(kvbase + k_kvo) * HD + k_dc * 8;
        ka0 = *(const f32x4*)(kp + 0);
        ka1 = *(const f32x4*)(kp + 4);
        kb0 = *(const f32x4*)(kp + 8);
        kb1 = *(const f32x4*)(kp + 12);
        const float* vp = V + base + (size_t)(kvbase + v_kv0) * HD + v_db;
        va0 = *(const f32x4*)(vp + 0);
        va1 = *(const f32x4*)(vp + 4);
        vb0 = *(const f32x4*)(vp + HD);
        vb1 = *(const f32x4*)(vp + HD + 4);
    };
    auto WRITET = [&](int b) {
        char* Kl = smraw + b * 16384;
        char* Vl = Kl + 8192;
        union { short8 s; unsigned u[4]; } c0, c1;
        c0.u[0] = pk2(ka0[0], ka0[1]); c0.u[1] = pk2(ka0[2], ka0[3]);
        c0.u[2] = pk2(ka1[0], ka1[1]); c0.u[3] = pk2(ka1[2], ka1[3]);
        c1.u[0] = pk2(kb0[0], kb0[1]); c1.u[1] = pk2(kb0[2], kb0[3]);
        c1.u[2] = pk2(kb1[0], kb1[1]); c1.u[3] = pk2(kb1[2], kb1[3]);
        const int r7 = k_row & 7;
        *(short8*)(Kl + ((k_row * 8 + (k_dc ^ r7)) << 4))       = c0.s;
        *(short8*)(Kl + ((k_row * 8 + ((k_dc + 1) ^ r7)) << 4)) = c1.s;
        const int u  = v_kv0 >> 3;
        const int wo = (v_kv0 & 7) * 2;
        #pragma unroll
        for (int i = 0; i < 4; ++i) {
            const int d = v_db + i;
            *(unsigned*)(Vl + ((d * 8 + (u ^ (d & 7))) << 4) + wo) = pk2(va0[i], vb0[i]);
        }
        #pragma unroll
        for (int i = 0; i < 4; ++i) {
            const int d = v_db + 4 + i;
            *(unsigned*)(Vl + ((d * 8 + (u ^ (d & 7))) << 4) + wo) = pk2(va1[i], vb1[i]);
        }
    };

    const float SC = 0.18033688011112042f;   // 0.125 * log2(e)

    #pragma unroll 1
    for (int tile = 0; tile < 2; ++tile) {
        const int qbase = (tile == 0 ? 31 - p : p) * 64;
        const int wq = qbase + w * 16;       // wave's 16 q rows

        // ---- Q fragment for this tile ----
        short8 qf[2];
        {
            const float* qp = Q + base + (size_t)(wq + r16) * HD + 8 * g;
            #pragma unroll
            for (int c = 0; c < 2; ++c) {
                f32x4 a = *(const f32x4*)(qp + c * 32);
                f32x4 b = *(const f32x4*)(qp + c * 32 + 4);
                union { short8 s; unsigned u[4]; } t;
                t.u[0] = pk2(a[0] * SC, a[1] * SC);
                t.u[1] = pk2(a[2] * SC, a[3] * SC);
                t.u[2] = pk2(b[0] * SC, b[1] * SC);
                t.u[3] = pk2(b[2] * SC, b[3] * SC);
                qf[c] = t.s;
            }
        }

        f32x4 oacc[4] = {};
        f32x4 lacc = {};
        float mrun = -1e30f;

        const int nkvb = (qbase + 64) >> 6;

        __syncthreads();                 // LDS safe to overwrite (tile switch)
        LOADT(0);
        WRITET(0);
        __syncthreads();

        for (int kvb = 0; kvb < nkvb; ++kvb) {
            const int kvbase = kvb << 6;
            const int buf = kvb & 1;
            const bool more = (kvb + 1 < nkvb);

            if (more) LOADT((kvb + 1) << 6);   // issue prefetch loads early

            if (kvbase <= wq + 15) {           // wave-uniform causal activity
                const char* Kl = smraw + buf * 16384;
                const char* Vl = Kl + 8192;

                // ---- QK^T: S^T = K.Q over 64 kv (2 c2 x 2 t), D=64 (2 c) ----
                f32x4 sa[2][2];
                #pragma unroll
                for (int c2 = 0; c2 < 2; ++c2)
                    #pragma unroll
                    for (int t = 0; t < 2; ++t)
                        sa[c2][t] = (f32x4){0.f, 0.f, 0.f, 0.f};
                __builtin_amdgcn_s_setprio(1);
                #pragma unroll
                for (int c2 = 0; c2 < 2; ++c2)
                    #pragma unroll
                    for (int t = 0; t < 2; ++t)
                        #pragma unroll
                        for (int c = 0; c < 2; ++c) {
                            const int row = c2 * 32 + t * 16 + r16;
                            short8 kf = *(const short8*)(Kl + ((row * 8 + ((4 * c + g) ^ (row & 7))) << 4));
                            sa[c2][t] = __builtin_amdgcn_mfma_f32_16x16x32_bf16(kf, qf[c], sa[c2][t], 0, 0, 0);
                        }
                __builtin_amdgcn_s_setprio(0);

                // ---- causal mask (diagonal region only) ----
                if (kvbase + 63 > wq) {
                    const int qrow = wq + r16;
                    #pragma unroll
                    for (int c2 = 0; c2 < 2; ++c2)
                        #pragma unroll
                        for (int t = 0; t < 2; ++t)
                            #pragma unroll
                            for (int r = 0; r < 4; ++r) {
                                const int kv = kvbase + c2 * 32 + 8 * g + 4 * t + r;
                                if (kv > qrow) sa[c2][t][r] = -1e30f;
                            }
                }

                // ---- stats + defer-rescale (exp2 domain, THR=8) ----
                float mloc = sa[0][0][0];
                #pragma unroll
                for (int c2 = 0; c2 < 2; ++c2)
                    #pragma unroll
                    for (int t = 0; t < 2; ++t)
                        #pragma unroll
                        for (int r = 0; r < 4; ++r)
                            mloc = fmaxf(mloc, sa[c2][t][r]);
                mloc = fmaxf(mloc, __shfl_xor(mloc, 16));
                mloc = fmaxf(mloc, __shfl_xor(mloc, 32));
                const float mnew = fmaxf(mrun, mloc);
                if (!__all(mnew - mrun <= 8.0f)) {
                    const float alpha = __builtin_amdgcn_exp2f(mrun - mnew);
                    mrun = mnew;
                    lacc[0] *= alpha;          // only [0] is ever read
                    #pragma unroll
                    for (int dt = 0; dt < 4; ++dt) oacc[dt] *= alpha;
                }
                #pragma unroll
                for (int c2 = 0; c2 < 2; ++c2)
                    #pragma unroll
                    for (int t = 0; t < 2; ++t)
                        #pragma unroll
                        for (int r = 0; r < 4; ++r)
                            sa[c2][t][r] = __builtin_amdgcn_exp2f(sa[c2][t][r] - mrun);

                // ---- PV: O^T += V^T . P ; l += ones . P (MFMA row-sum) ----
                #pragma unroll
                for (int c2 = 0; c2 < 2; ++c2) {
                    union { short8 s; unsigned u[4]; } pf;
                    pf.u[0] = pk2(sa[c2][0][0], sa[c2][0][1]);
                    pf.u[1] = pk2(sa[c2][0][2], sa[c2][0][3]);
                    pf.u[2] = pk2(sa[c2][1][0], sa[c2][1][1]);
                    pf.u[3] = pk2(sa[c2][1][2], sa[c2][1][3]);
                    __builtin_amdgcn_s_setprio(1);
                    lacc = __builtin_amdgcn_mfma_f32_16x16x32_bf16(ones, pf.s, lacc, 0, 0, 0);
                    #pragma unroll
                    for (int dt = 0; dt < 4; ++dt) {
                        const int row = dt * 16 + r16;
                        short8 vf = *(const short8*)(Vl + ((row * 8 + ((c2 * 4 + g) ^ (row & 7))) << 4));
                        oacc[dt] = __builtin_amdgcn_mfma_f32_16x16x32_bf16(vf, pf.s, oacc[dt], 0, 0, 0);
                    }
                    __builtin_amdgcn_s_setprio(0);
                }
            }

            if (more) {
                WRITET(buf ^ 1);               // cvt+write prefetched tile
                __syncthreads();
            }
        }

        // ---- epilogue: direct coalesced stores from the accumulator ----
        {
            const float inv = 1.0f / lacc[0];
            float* op = O + base + (size_t)(wq + r16) * HD + 4 * g;
            #pragma unroll
            for (int dt = 0; dt < 4; ++dt) {
                f32x4 vv = oacc[dt] * inv;
                *(f32x4*)(op + dt * 16) = vv;
            }
        }
    }
}

extern "C" void kernel_launch(void* const* d_in, const int* in_sizes, int n_in,
                              void* d_out, int out_size, void* d_ws, size_t ws_size,
                              hipStream_t stream) {
    (void)in_sizes; (void)n_in; (void)out_size; (void)d_ws; (void)ws_size;
    const float* q = (const float*)d_in[0];
    const float* k = (const float*)d_in[1];
    const float* v = (const float*)d_in[2];
    float* o = (float*)d_out;
    sdpa_kernel<<<dim3(64 * 16), dim3(256), 0, stream>>>(q, k, v, o);
}